// Round 5
// baseline (165.742 us; speedup 1.0000x reference)
//
#include <hip/hip_runtime.h>
#include <hip/hip_bf16.h>
#include <math.h>

#define GN 12288
#define GE 196608
#define GK 1433
#define GC 32
#define CAP 64        // fixed CSR capacity/node; max degree ~38
#define NCHUNK 45     // ceil(1433/32) k-chunks of 32
#define NGRP 180      // ceil(1433/8) k-groups of 8 (W packing granularity)
#define GEMMB 768     // 16 rows per gemm block
#define EDGEB 768     // 768*256 = 196608 = GE exactly
#define PACKB 23      // 23*256 >= NGRP*GC = 5760
#define ZEROB 96      // 96*256 = 24576 = 2*GN exactly

typedef __attribute__((ext_vector_type(8))) short bf16x8;
typedef __attribute__((ext_vector_type(4))) float f32x4;

static __device__ inline unsigned short f2bf(float f) {
    unsigned u = __float_as_uint(f);
    return (unsigned short)((u + 0x7fffu + ((u >> 16) & 1u)) >> 16);
}
static __device__ inline float bf2f(unsigned short h) {
    return __uint_as_float(((unsigned)h) << 16);
}
// HW RNE conversion — compiler emits v_cvt bf16 (same rounding as f2bf)
static __device__ inline unsigned short f2bf_hw(float f) {
    return __builtin_bit_cast(unsigned short, __float2bfloat16(f));
}

// ---------------- prep: zero cnt/deg + pack W1 -> bf16 hi/lo fragments ------
__global__ __launch_bounds__(256) void prep_kernel(const float* __restrict__ W1,
                                                   unsigned* __restrict__ zbuf,
                                                   unsigned short* __restrict__ Whb,
                                                   unsigned short* __restrict__ Wlb) {
    int t = threadIdx.x, b = blockIdx.x;
    if (b < PACKB) {
        int idx = b * 256 + t;           // idx = g*32 + c
        if (idx < NGRP * GC) {
            int g = idx >> 5, c = idx & 31;
            bf16x8 vh, vl;
            #pragma unroll
            for (int j = 0; j < 8; ++j) {
                int k = g * 8 + j;
                float f = (k < GK) ? W1[(size_t)k * GC + c] : 0.f;
                unsigned short hh = f2bf(f);
                vh[j] = (short)hh;
                vl[j] = (short)f2bf(f - bf2f(hh));
            }
            *(bf16x8*)(Whb + (size_t)idx * 8) = vh;
            *(bf16x8*)(Wlb + (size_t)idx * 8) = vl;
        }
    } else {
        int idx = (b - PACKB) * 256 + t; // zero cnt+deg (contiguous, 2*GN words)
        zbuf[idx] = 0u;
    }
}

// ---------------- fused: gemm (blocks 0..GEMMB) + graph build ----------------
// R3 post-mortem: VGPR=72 proved the compiler folded the "distance-3" buffers
// and sank all loads to their uses (depth ~1). This version pins the schedule:
// depth-5 rotation, sched_barrier(0) at each stage boundary so chunk q+4's
// loads are ISSUED before chunk q's MFMAs. Expect VGPR ~140-160.
// (R4 bench was an infra failure — container acquisition; resubmitting.)
__global__ __launch_bounds__(256) void fused_kernel(const float* __restrict__ x,
                                                    const int* __restrict__ ei,
                                                    const unsigned short* __restrict__ Whb,
                                                    const unsigned short* __restrict__ Wlb,
                                                    float* __restrict__ xw,
                                                    unsigned* __restrict__ cnt,
                                                    unsigned* __restrict__ deg,
                                                    unsigned* __restrict__ adjF) {
    int t = threadIdx.x, bid = blockIdx.x;

    if (bid >= GEMMB) {
        // ---- graph build: one edge per thread ----
        int e = (bid - GEMMB) * 256 + t;
        int src = ei[e];
        int dst = ei[GE + e];
        unsigned pos = atomicAdd(&cnt[src], 1u);
        if (pos < CAP) adjF[(unsigned)src * CAP + pos] = (unsigned)dst;
        atomicAdd(&deg[dst], 1u);
        return;
    }

    __shared__ float red[4][16][32];
    int lane = t & 63, w = t >> 6;
    int quad = lane >> 4, l15 = lane & 15;
    int row = bid * 16 + l15;
    const float* xr = x + (size_t)row * GK;
    f32x4 acc0 = {}, acc1 = {};
    int qs = (w * NCHUNK) >> 2;
    int qe = ((w + 1) * NCHUNK) >> 2;   // sizes 11,11,11,12

    float aA[8], aB[8], aC[8], aD[8], aE[8];
    bf16x8 hA0, hA1, lA0, lA1;
    bf16x8 hB0, hB1, lB0, lB1;
    bf16x8 hC0, hC1, lC0, lC1;
    bf16x8 hD0, hD1, lD0, lD1;
    bf16x8 hE0, hE1, lE0, lE1;

#define LOADX(A8, q) { \
    int kq = (q) * 32 + quad * 8; \
    const float* p = xr + kq; \
    if (kq + 8 <= GK) { \
        _Pragma("unroll") for (int j = 0; j < 8; ++j) A8[j] = p[j]; \
    } else { \
        _Pragma("unroll") for (int j = 0; j < 8; ++j) A8[j] = (kq + j < GK) ? p[j] : 0.f; \
    } }

#define LOADW(H0, H1, L0, L1, q) { \
    int g = (q) * 4 + quad; \
    H0 = *(const bf16x8*)(Whb + (size_t)g * 256 + l15 * 8); \
    H1 = *(const bf16x8*)(Whb + (size_t)g * 256 + 128 + l15 * 8); \
    L0 = *(const bf16x8*)(Wlb + (size_t)g * 256 + l15 * 8); \
    L1 = *(const bf16x8*)(Wlb + (size_t)g * 256 + 128 + l15 * 8); \
    }

#define COMP(A8, H0, H1, L0, L1) { \
    bf16x8 ah, al; \
    _Pragma("unroll") for (int j = 0; j < 8; ++j) { \
        unsigned short hh = f2bf_hw(A8[j]); \
        ah[j] = (short)hh; \
        al[j] = (short)f2bf_hw(A8[j] - bf2f(hh)); \
    } \
    acc0 = __builtin_amdgcn_mfma_f32_16x16x32_bf16(ah, H0, acc0, 0, 0, 0); \
    acc1 = __builtin_amdgcn_mfma_f32_16x16x32_bf16(ah, H1, acc1, 0, 0, 0); \
    acc0 = __builtin_amdgcn_mfma_f32_16x16x32_bf16(ah, L0, acc0, 0, 0, 0); \
    acc1 = __builtin_amdgcn_mfma_f32_16x16x32_bf16(ah, L1, acc1, 0, 0, 0); \
    acc0 = __builtin_amdgcn_mfma_f32_16x16x32_bf16(al, H0, acc0, 0, 0, 0); \
    acc1 = __builtin_amdgcn_mfma_f32_16x16x32_bf16(al, H1, acc1, 0, 0, 0); \
    }

#define SB() __builtin_amdgcn_sched_barrier(0)

    // prologue: fill pipeline with chunks qs..qs+3 (every wave has >=11 chunks)
    int q = qs;
    LOADX(aA, q);     LOADW(hA0, hA1, lA0, lA1, q);
    LOADX(aB, q + 1); LOADW(hB0, hB1, lB0, lB1, q + 1);
    LOADX(aC, q + 2); LOADW(hC0, hC1, lC0, lC1, q + 2);
    LOADX(aD, q + 3); LOADW(hD0, hD1, lD0, lD1, q + 3);
    SB();
    // steady state: issue chunk q+4's loads, pin boundary, compute chunk q
    while (true) {
        if (q + 4 < qe) { LOADX(aE, q + 4); LOADW(hE0, hE1, lE0, lE1, q + 4); }
        SB(); COMP(aA, hA0, hA1, lA0, lA1); SB();
        ++q; if (q >= qe) break;
        if (q + 4 < qe) { LOADX(aA, q + 4); LOADW(hA0, hA1, lA0, lA1, q + 4); }
        SB(); COMP(aB, hB0, hB1, lB0, lB1); SB();
        ++q; if (q >= qe) break;
        if (q + 4 < qe) { LOADX(aB, q + 4); LOADW(hB0, hB1, lB0, lB1, q + 4); }
        SB(); COMP(aC, hC0, hC1, lC0, lC1); SB();
        ++q; if (q >= qe) break;
        if (q + 4 < qe) { LOADX(aC, q + 4); LOADW(hC0, hC1, lC0, lC1, q + 4); }
        SB(); COMP(aD, hD0, hD1, lD0, lD1); SB();
        ++q; if (q >= qe) break;
        if (q + 4 < qe) { LOADX(aD, q + 4); LOADW(hD0, hD1, lD0, lD1, q + 4); }
        SB(); COMP(aE, hE0, hE1, lE0, lE1); SB();
        ++q; if (q >= qe) break;
    }

    // C layout 16x16: col = lane&15, row = quad*4 + i
    #pragma unroll
    for (int i = 0; i < 4; ++i) {
        red[w][quad * 4 + i][l15] = acc0[i];
        red[w][quad * 4 + i][16 + l15] = acc1[i];
    }
    __syncthreads();
    int r0 = t >> 5, c0 = t & 31;
    float s0 = red[0][r0][c0] + red[1][r0][c0] + red[2][r0][c0] + red[3][r0][c0];
    int r1 = r0 + 8;
    float s1 = red[0][r1][c0] + red[1][r1][c0] + red[2][r1][c0] + red[3][r1][c0];
    xw[(size_t)bid * 512 + t] = s0;
    xw[(size_t)bid * 512 + 256 + t] = s1;
}

// ---------------- GCN gather -> h (inline rsqrt of deg) ----------------
__global__ __launch_bounds__(256) void gcn_kernel(const float* __restrict__ xw,
                                                  const unsigned* __restrict__ deg,
                                                  const unsigned* __restrict__ cnt,
                                                  const unsigned* __restrict__ adjF,
                                                  const float* __restrict__ b1,
                                                  float* __restrict__ h) {
    int w = threadIdx.x >> 6;
    int lane = threadIdx.x & 63;
    int i = blockIdx.x * 4 + w;
    int f = lane & 31, half = lane >> 5;
    unsigned cl = min(cnt[i], (unsigned)CAP);
    const unsigned* ai = adjF + (unsigned)i * CAP;
    float acc = 0.f;
    for (unsigned j = half; j < cl; j += 8) {
        unsigned lim = cl - 1;
        unsigned j1 = j + 2, j2 = j + 4, j3 = j + 6;
        unsigned d0 = ai[j];
        unsigned d1 = ai[min(j1, lim)];
        unsigned d2 = ai[min(j2, lim)];
        unsigned d3 = ai[min(j3, lim)];
        float m1 = j1 < cl ? 1.f : 0.f;
        float m2 = j2 < cl ? 1.f : 0.f;
        float m3 = j3 < cl ? 1.f : 0.f;
        acc += xw[(size_t)d0 * GC + f] * rsqrtf((float)(deg[d0] + 1u));
        acc += m1 * xw[(size_t)d1 * GC + f] * rsqrtf((float)(deg[d1] + 1u));
        acc += m2 * xw[(size_t)d2 * GC + f] * rsqrtf((float)(deg[d2] + 1u));
        acc += m3 * xw[(size_t)d3 * GC + f] * rsqrtf((float)(deg[d3] + 1u));
    }
    acc += __shfl_xor(acc, 32, 64);
    float disi = rsqrtf((float)(deg[i] + 1u));
    float v = b1[f] + disi * (disi * xw[(size_t)i * GC + f] + acc);
    if (half == 0) h[(size_t)i * GC + f] = fmaxf(v, 0.f);
}

// ---------------- SAGE gather + fused head ----------------
__global__ __launch_bounds__(256) void sage_kernel(const float* __restrict__ h,
                                                   const unsigned* __restrict__ cnt,
                                                   const unsigned* __restrict__ adjF,
                                                   const float* __restrict__ Wl,
                                                   const float* __restrict__ bl,
                                                   const float* __restrict__ Wr,
                                                   const float* __restrict__ br,
                                                   const float* __restrict__ W3,
                                                   const float* __restrict__ b3,
                                                   float* __restrict__ out) {
    __shared__ float sh[4][64];
    __shared__ float so[4][16];
    int w = threadIdx.x >> 6, lane = threadIdx.x & 63;
    int i = blockIdx.x * 4 + w;
    int f = lane & 31, half = lane >> 5;
    unsigned ci = cnt[i];
    unsigned cl = min(ci, (unsigned)CAP);
    const unsigned* ai = adjF + (unsigned)i * CAP;
    float acc = 0.f;
    for (unsigned j = half; j < cl; j += 8) {
        unsigned lim = cl - 1;
        unsigned j1 = j + 2, j2 = j + 4, j3 = j + 6;
        unsigned d0 = ai[j];
        unsigned d1 = ai[min(j1, lim)];
        unsigned d2 = ai[min(j2, lim)];
        unsigned d3 = ai[min(j3, lim)];
        float m1 = j1 < cl ? 1.f : 0.f;
        float m2 = j2 < cl ? 1.f : 0.f;
        float m3 = j3 < cl ? 1.f : 0.f;
        acc += h[(size_t)d0 * GC + f];
        acc += m1 * h[(size_t)d1 * GC + f];
        acc += m2 * h[(size_t)d2 * GC + f];
        acc += m3 * h[(size_t)d3 * GC + f];
    }
    acc += __shfl_xor(acc, 32, 64);
    float agg = ci ? acc / (float)ci : 0.f;
    float hv = h[(size_t)i * GC + f];
    if (half == 0) { sh[w][f] = hv; sh[w][32 + f] = agg; }
    __syncthreads();
    int c = lane;
    float hid = 0.f;
    if (c < 16) {
        hid = bl[c] + br[c];
        #pragma unroll
        for (int ff = 0; ff < 32; ++ff)
            hid += sh[w][ff] * Wl[ff * 16 + c] + sh[w][32 + ff] * Wr[ff * 16 + c];
        hid = fmaxf(hid, 0.f);
    }
    float n2 = hid * hid;
    n2 += __shfl_xor(n2, 1, 64);
    n2 += __shfl_xor(n2, 2, 64);
    n2 += __shfl_xor(n2, 4, 64);
    n2 += __shfl_xor(n2, 8, 64);
    float o = hid / (sqrtf(n2) + 1e-6f);
    if (c < 16) so[w][c] = o;
    __syncthreads();
    float logit = -INFINITY;
    if (lane < 7) {
        logit = b3[lane];
        #pragma unroll
        for (int cc = 0; cc < 16; ++cc) logit += so[w][cc] * W3[cc * 7 + lane];
    }
    float m = logit;
    m = fmaxf(m, __shfl_xor(m, 1, 64));
    m = fmaxf(m, __shfl_xor(m, 2, 64));
    m = fmaxf(m, __shfl_xor(m, 4, 64));
    float e = expf(logit - m);
    float s = e;
    s += __shfl_xor(s, 1, 64);
    s += __shfl_xor(s, 2, 64);
    s += __shfl_xor(s, 4, 64);
    if (lane < 7) out[(size_t)i * 7 + lane] = e / s;
}

extern "C" void kernel_launch(void* const* d_in, const int* in_sizes, int n_in,
                              void* d_out, int out_size, void* d_ws, size_t ws_size,
                              hipStream_t stream) {
    const float* x  = (const float*)d_in[0];
    const int*   ei = (const int*)d_in[1];
    const float* W1 = (const float*)d_in[2];
    const float* b1 = (const float*)d_in[3];
    const float* Wl = (const float*)d_in[4];
    const float* bl = (const float*)d_in[5];
    const float* Wr = (const float*)d_in[6];
    const float* br = (const float*)d_in[7];
    const float* W3 = (const float*)d_in[8];
    const float* b3 = (const float*)d_in[9];
    float* out = (float*)d_out;

    char* ws = (char*)d_ws;
    const size_t S = (size_t)GN * GC * 4;                  // 1.57 MB
    float*    xw   = (float*)(ws);
    unsigned* cnt  = (unsigned*)(ws + S);
    unsigned* deg  = cnt + GN;
    float*    h    = (float*)(deg + GN);
    unsigned* adjF = (unsigned*)((char*)h + S);            // GN*CAP*4 = 3 MB
    unsigned short* Whb = (unsigned short*)((char*)adjF + (size_t)GN * CAP * 4);
    unsigned short* Wlb = Whb + (size_t)NGRP * GC * 8;     // 92160 B each

    prep_kernel<<<PACKB + ZEROB, 256, 0, stream>>>(W1, cnt, Whb, Wlb);
    fused_kernel<<<GEMMB + EDGEB, 256, 0, stream>>>(x, ei, Whb, Wlb, xw, cnt, deg, adjF);
    gcn_kernel<<<GN / 4, 256, 0, stream>>>(xw, deg, cnt, adjF, b1, h);
    sage_kernel<<<GN / 4, 256, 0, stream>>>(h, cnt, adjF, Wl, bl, Wr, br, W3, b3, out);
}

// Round 6
// 154.138 us; speedup vs baseline: 1.0753x; 1.0753x over previous
//
#include <hip/hip_runtime.h>
#include <hip/hip_bf16.h>
#include <math.h>

#define GN 12288
#define GE 196608
#define GK 1433
#define GC 32
#define CAP 64        // fixed CSR capacity/node; max degree ~38
#define NGRP 192      // k-groups of 8, zero-padded to 1536 = 3 sweeps * 512
#define GEMMB 768     // 16 rows per gemm block
#define EDGEB 768     // 768*256 = 196608 = GE exactly
#define PACKB 24      // 24*256 = 6144 = NGRP*GC exactly
#define ZEROB 96      // 96*256 = 24576 = 2*GN exactly
#define XSTR 516      // LDS row stride (floats): 512 + 4 pad -> 16B-aligned, bank-optimal

typedef __attribute__((ext_vector_type(8))) short bf16x8;
typedef __attribute__((ext_vector_type(4))) float f32x4;
// 4-byte-aligned float4 for x rows (row stride 5732 B is only 4B-aligned)
typedef float f32x4a __attribute__((ext_vector_type(4), aligned(4)));

static __device__ inline unsigned short f2bf(float f) {
    unsigned u = __float_as_uint(f);
    return (unsigned short)((u + 0x7fffu + ((u >> 16) & 1u)) >> 16);
}
static __device__ inline float bf2f(unsigned short h) {
    return __uint_as_float(((unsigned)h) << 16);
}
// HW RNE conversion — same rounding as f2bf
static __device__ inline unsigned short f2bf_hw(float f) {
    return __builtin_bit_cast(unsigned short, __float2bfloat16(f));
}

// ---------------- prep: zero cnt/deg + pack W1 -> bf16 hi/lo fragments ------
// entry (g,c) holds W1[g*8+j][c] j=0..7 as bf16x8; zero-padded for k >= GK.
__global__ __launch_bounds__(256) void prep_kernel(const float* __restrict__ W1,
                                                   unsigned* __restrict__ zbuf,
                                                   unsigned short* __restrict__ Whb,
                                                   unsigned short* __restrict__ Wlb) {
    int t = threadIdx.x, b = blockIdx.x;
    if (b < PACKB) {
        int idx = b * 256 + t;           // idx = g*32 + c
        int g = idx >> 5, c = idx & 31;
        bf16x8 vh, vl;
        #pragma unroll
        for (int j = 0; j < 8; ++j) {
            int k = g * 8 + j;
            float f = (k < GK) ? W1[(size_t)k * GC + c] : 0.f;
            unsigned short hh = f2bf(f);
            vh[j] = (short)hh;
            vl[j] = (short)f2bf(f - bf2f(hh));
        }
        *(bf16x8*)(Whb + (size_t)idx * 8) = vh;
        *(bf16x8*)(Wlb + (size_t)idx * 8) = vl;
    } else {
        int idx = (b - PACKB) * 256 + t; // zero cnt+deg (contiguous, 2*GN words)
        zbuf[idx] = 0u;
    }
}

// ---------------- fused: gemm (blocks 0..GEMMB) + graph build ----------------
// R5 post-mortem: the x-read was 16 scattered 128B streams/wave at stride
// 5732B -> ~25% HBM efficiency; prefetch depth can't fix access SHAPE.
// Now: block's 16 contiguous rows staged to LDS in 3 sweeps of 512 cols with
// fully coalesced loads (T14 issue-early/write-late), fragments read from LDS
// (stride 516: bank-conflict-free, 16B-aligned). SB pins removed (m141).
__global__ __launch_bounds__(256) void fused_kernel(const float* __restrict__ x,
                                                    const int* __restrict__ ei,
                                                    const unsigned short* __restrict__ Whb,
                                                    const unsigned short* __restrict__ Wlb,
                                                    float* __restrict__ xw,
                                                    unsigned* __restrict__ cnt,
                                                    unsigned* __restrict__ deg,
                                                    unsigned* __restrict__ adjF) {
    int t = threadIdx.x, bid = blockIdx.x;

    if (bid >= GEMMB) {
        // ---- graph build: one edge per thread ----
        int e = (bid - GEMMB) * 256 + t;
        int src = ei[e];
        int dst = ei[GE + e];
        unsigned pos = atomicAdd(&cnt[src], 1u);
        if (pos < CAP) adjF[(unsigned)src * CAP + pos] = (unsigned)dst;
        atomicAdd(&deg[dst], 1u);
        return;
    }

    __shared__ __align__(16) float xs[16][XSTR];   // 33024 B; red overlays later
    int lane = t & 63, w = t >> 6;
    int quad = lane >> 4, l15 = lane & 15;
    const float* xb = x + (size_t)bid * 16 * GK;
    f32x4 acc0 = {}, acc1 = {};

    // staging map: thread covers rows {r0, r0+2, ..., r0+14} at fixed pos
    int r0 = t >> 7;            // 0 or 1
    int pos = t & 127;          // 0..127 -> 4-float column group
    f32x4 g0, g1, g2, g3, g4, g5, g6, g7;

#define LOADG(K0) { \
    const float* pp = xb + (size_t)r0 * GK + (K0) + pos * 4; \
    g0 = *(const f32x4a*)(pp); \
    g1 = *(const f32x4a*)(pp + 2 * GK); \
    g2 = *(const f32x4a*)(pp + 4 * GK); \
    g3 = *(const f32x4a*)(pp + 6 * GK); \
    g4 = *(const f32x4a*)(pp + 8 * GK); \
    g5 = *(const f32x4a*)(pp + 10 * GK); \
    g6 = *(const f32x4a*)(pp + 12 * GK); \
    g7 = *(const f32x4a*)(pp + 14 * GK); }

    // guarded variant for the tail sweep (K0=1024: k up to 1535 >= GK)
#define LG1(DST, ROFF, PP, KB) { \
    const float* q_ = (PP) + (size_t)(ROFF) * GK; \
    if ((KB) + 4 <= GK) DST = *(const f32x4a*)q_; \
    else { \
        DST[0] = ((KB) + 0 < GK) ? q_[0] : 0.f; \
        DST[1] = ((KB) + 1 < GK) ? q_[1] : 0.f; \
        DST[2] = ((KB) + 2 < GK) ? q_[2] : 0.f; \
        DST[3] = ((KB) + 3 < GK) ? q_[3] : 0.f; } }

#define LOADG_TAIL(K0) { \
    const float* pp = xb + (size_t)r0 * GK + (K0) + pos * 4; \
    int kb = (K0) + pos * 4; \
    LG1(g0, 0, pp, kb)  LG1(g1, 2, pp, kb)  LG1(g2, 4, pp, kb)  LG1(g3, 6, pp, kb) \
    LG1(g4, 8, pp, kb)  LG1(g5, 10, pp, kb) LG1(g6, 12, pp, kb) LG1(g7, 14, pp, kb) }

#define STOREL() { \
    float* lp = &xs[r0][pos * 4]; \
    *(f32x4*)(lp)              = g0; \
    *(f32x4*)(lp + 2 * XSTR)   = g1; \
    *(f32x4*)(lp + 4 * XSTR)   = g2; \
    *(f32x4*)(lp + 6 * XSTR)   = g3; \
    *(f32x4*)(lp + 8 * XSTR)   = g4; \
    *(f32x4*)(lp + 10 * XSTR)  = g5; \
    *(f32x4*)(lp + 12 * XSTR)  = g6; \
    *(f32x4*)(lp + 14 * XSTR)  = g7; }

    // wave w computes local cols [w*128, w*128+128) of each sweep (wave-split K)
#define COMPUTE(S) { \
    _Pragma("unroll") \
    for (int c = 0; c < 4; ++c) { \
        int kl = w * 128 + c * 32 + quad * 8; \
        const float* ap = &xs[l15][kl]; \
        f32x4 x0 = *(const f32x4*)ap; \
        f32x4 x1 = *(const f32x4*)(ap + 4); \
        bf16x8 ah, al; \
        _Pragma("unroll") for (int j = 0; j < 4; ++j) { \
            unsigned short hh = f2bf_hw(x0[j]); \
            ah[j] = (short)hh; al[j] = (short)f2bf_hw(x0[j] - bf2f(hh)); } \
        _Pragma("unroll") for (int j = 0; j < 4; ++j) { \
            unsigned short hh = f2bf_hw(x1[j]); \
            ah[4 + j] = (short)hh; al[4 + j] = (short)f2bf_hw(x1[j] - bf2f(hh)); } \
        int gg = (S) * 64 + w * 16 + c * 4 + quad; \
        bf16x8 H0 = *(const bf16x8*)(Whb + (size_t)gg * 256 + l15 * 8); \
        bf16x8 H1 = *(const bf16x8*)(Whb + (size_t)gg * 256 + 128 + l15 * 8); \
        bf16x8 L0 = *(const bf16x8*)(Wlb + (size_t)gg * 256 + l15 * 8); \
        bf16x8 L1 = *(const bf16x8*)(Wlb + (size_t)gg * 256 + 128 + l15 * 8); \
        acc0 = __builtin_amdgcn_mfma_f32_16x16x32_bf16(ah, H0, acc0, 0, 0, 0); \
        acc1 = __builtin_amdgcn_mfma_f32_16x16x32_bf16(ah, H1, acc1, 0, 0, 0); \
        acc0 = __builtin_amdgcn_mfma_f32_16x16x32_bf16(ah, L0, acc0, 0, 0, 0); \
        acc1 = __builtin_amdgcn_mfma_f32_16x16x32_bf16(ah, L1, acc1, 0, 0, 0); \
        acc0 = __builtin_amdgcn_mfma_f32_16x16x32_bf16(al, H0, acc0, 0, 0, 0); \
        acc1 = __builtin_amdgcn_mfma_f32_16x16x32_bf16(al, H1, acc1, 0, 0, 0); \
    } }

    // ---- sweep pipeline: stage s, prefetch s+1 under compute of s ----
    LOADG(0);
    STOREL();
    __syncthreads();
    LOADG(512);            // issue-early (T14): hides under COMPUTE(0)
    COMPUTE(0);
    __syncthreads();       // all waves done reading sweep 0
    STOREL();              // write-late (vmcnt on g regs inserted by compiler)
    __syncthreads();
    LOADG_TAIL(1024);
    COMPUTE(1);
    __syncthreads();
    STOREL();
    __syncthreads();
    COMPUTE(2);
    __syncthreads();       // before red overlays xs

    // ---- cross-wave reduce (red overlays xs; all xs reads complete) ----
    float (*red)[16][32] = (float (*)[16][32])(&xs[0][0]);
    #pragma unroll
    for (int i = 0; i < 4; ++i) {
        red[w][quad * 4 + i][l15] = acc0[i];
        red[w][quad * 4 + i][16 + l15] = acc1[i];
    }
    __syncthreads();
    int rr0 = t >> 5, cc0 = t & 31;
    float s0 = red[0][rr0][cc0] + red[1][rr0][cc0] + red[2][rr0][cc0] + red[3][rr0][cc0];
    int rr1 = rr0 + 8;
    float s1 = red[0][rr1][cc0] + red[1][rr1][cc0] + red[2][rr1][cc0] + red[3][rr1][cc0];
    xw[(size_t)bid * 512 + t] = s0;
    xw[(size_t)bid * 512 + 256 + t] = s1;
}

// ---------------- GCN gather -> h (inline rsqrt of deg) ----------------
__global__ __launch_bounds__(256) void gcn_kernel(const float* __restrict__ xw,
                                                  const unsigned* __restrict__ deg,
                                                  const unsigned* __restrict__ cnt,
                                                  const unsigned* __restrict__ adjF,
                                                  const float* __restrict__ b1,
                                                  float* __restrict__ h) {
    int w = threadIdx.x >> 6;
    int lane = threadIdx.x & 63;
    int i = blockIdx.x * 4 + w;
    int f = lane & 31, half = lane >> 5;
    unsigned cl = min(cnt[i], (unsigned)CAP);
    const unsigned* ai = adjF + (unsigned)i * CAP;
    float acc = 0.f;
    for (unsigned j = half; j < cl; j += 8) {
        unsigned lim = cl - 1;
        unsigned j1 = j + 2, j2 = j + 4, j3 = j + 6;
        unsigned d0 = ai[j];
        unsigned d1 = ai[min(j1, lim)];
        unsigned d2 = ai[min(j2, lim)];
        unsigned d3 = ai[min(j3, lim)];
        float m1 = j1 < cl ? 1.f : 0.f;
        float m2 = j2 < cl ? 1.f : 0.f;
        float m3 = j3 < cl ? 1.f : 0.f;
        acc += xw[(size_t)d0 * GC + f] * rsqrtf((float)(deg[d0] + 1u));
        acc += m1 * xw[(size_t)d1 * GC + f] * rsqrtf((float)(deg[d1] + 1u));
        acc += m2 * xw[(size_t)d2 * GC + f] * rsqrtf((float)(deg[d2] + 1u));
        acc += m3 * xw[(size_t)d3 * GC + f] * rsqrtf((float)(deg[d3] + 1u));
    }
    acc += __shfl_xor(acc, 32, 64);
    float disi = rsqrtf((float)(deg[i] + 1u));
    float v = b1[f] + disi * (disi * xw[(size_t)i * GC + f] + acc);
    if (half == 0) h[(size_t)i * GC + f] = fmaxf(v, 0.f);
}

// ---------------- SAGE gather + fused head ----------------
__global__ __launch_bounds__(256) void sage_kernel(const float* __restrict__ h,
                                                   const unsigned* __restrict__ cnt,
                                                   const unsigned* __restrict__ adjF,
                                                   const float* __restrict__ Wl,
                                                   const float* __restrict__ bl,
                                                   const float* __restrict__ Wr,
                                                   const float* __restrict__ br,
                                                   const float* __restrict__ W3,
                                                   const float* __restrict__ b3,
                                                   float* __restrict__ out) {
    __shared__ float sh[4][64];
    __shared__ float so[4][16];
    int w = threadIdx.x >> 6, lane = threadIdx.x & 63;
    int i = blockIdx.x * 4 + w;
    int f = lane & 31, half = lane >> 5;
    unsigned ci = cnt[i];
    unsigned cl = min(ci, (unsigned)CAP);
    const unsigned* ai = adjF + (unsigned)i * CAP;
    float acc = 0.f;
    for (unsigned j = half; j < cl; j += 8) {
        unsigned lim = cl - 1;
        unsigned j1 = j + 2, j2 = j + 4, j3 = j + 6;
        unsigned d0 = ai[j];
        unsigned d1 = ai[min(j1, lim)];
        unsigned d2 = ai[min(j2, lim)];
        unsigned d3 = ai[min(j3, lim)];
        float m1 = j1 < cl ? 1.f : 0.f;
        float m2 = j2 < cl ? 1.f : 0.f;
        float m3 = j3 < cl ? 1.f : 0.f;
        acc += h[(size_t)d0 * GC + f];
        acc += m1 * h[(size_t)d1 * GC + f];
        acc += m2 * h[(size_t)d2 * GC + f];
        acc += m3 * h[(size_t)d3 * GC + f];
    }
    acc += __shfl_xor(acc, 32, 64);
    float agg = ci ? acc / (float)ci : 0.f;
    float hv = h[(size_t)i * GC + f];
    if (half == 0) { sh[w][f] = hv; sh[w][32 + f] = agg; }
    __syncthreads();
    int c = lane;
    float hid = 0.f;
    if (c < 16) {
        hid = bl[c] + br[c];
        #pragma unroll
        for (int ff = 0; ff < 32; ++ff)
            hid += sh[w][ff] * Wl[ff * 16 + c] + sh[w][32 + ff] * Wr[ff * 16 + c];
        hid = fmaxf(hid, 0.f);
    }
    float n2 = hid * hid;
    n2 += __shfl_xor(n2, 1, 64);
    n2 += __shfl_xor(n2, 2, 64);
    n2 += __shfl_xor(n2, 4, 64);
    n2 += __shfl_xor(n2, 8, 64);
    float o = hid / (sqrtf(n2) + 1e-6f);
    if (c < 16) so[w][c] = o;
    __syncthreads();
    float logit = -INFINITY;
    if (lane < 7) {
        logit = b3[lane];
        #pragma unroll
        for (int cc = 0; cc < 16; ++cc) logit += so[w][cc] * W3[cc * 7 + lane];
    }
    float m = logit;
    m = fmaxf(m, __shfl_xor(m, 1, 64));
    m = fmaxf(m, __shfl_xor(m, 2, 64));
    m = fmaxf(m, __shfl_xor(m, 4, 64));
    float e = expf(logit - m);
    float s = e;
    s += __shfl_xor(s, 1, 64);
    s += __shfl_xor(s, 2, 64);
    s += __shfl_xor(s, 4, 64);
    if (lane < 7) out[(size_t)i * 7 + lane] = e / s;
}

extern "C" void kernel_launch(void* const* d_in, const int* in_sizes, int n_in,
                              void* d_out, int out_size, void* d_ws, size_t ws_size,
                              hipStream_t stream) {
    const float* x  = (const float*)d_in[0];
    const int*   ei = (const int*)d_in[1];
    const float* W1 = (const float*)d_in[2];
    const float* b1 = (const float*)d_in[3];
    const float* Wl = (const float*)d_in[4];
    const float* bl = (const float*)d_in[5];
    const float* Wr = (const float*)d_in[6];
    const float* br = (const float*)d_in[7];
    const float* W3 = (const float*)d_in[8];
    const float* b3 = (const float*)d_in[9];
    float* out = (float*)d_out;

    char* ws = (char*)d_ws;
    const size_t S = (size_t)GN * GC * 4;                  // 1.57 MB
    float*    xw   = (float*)(ws);
    unsigned* cnt  = (unsigned*)(ws + S);
    unsigned* deg  = cnt + GN;
    float*    h    = (float*)(deg + GN);
    unsigned* adjF = (unsigned*)((char*)h + S);            // GN*CAP*4 = 3 MB
    unsigned short* Whb = (unsigned short*)((char*)adjF + (size_t)GN * CAP * 4);
    unsigned short* Wlb = Whb + (size_t)NGRP * GC * 8;     // 98304 B each

    prep_kernel<<<PACKB + ZEROB, 256, 0, stream>>>(W1, cnt, Whb, Wlb);
    fused_kernel<<<GEMMB + EDGEB, 256, 0, stream>>>(x, ei, Whb, Wlb, xw, cnt, deg, adjF);
    gcn_kernel<<<GN / 4, 256, 0, stream>>>(xw, deg, cnt, adjF, b1, h);
    sage_kernel<<<GN / 4, 256, 0, stream>>>(h, cnt, adjF, Wl, bl, Wr, br, W3, b3, out);
}